// Round 1
// 351.534 us; speedup vs baseline: 1.1613x; 1.1613x over previous
//
#include <hip/hip_runtime.h>

#define CC 128
#define HH 80
#define WW 256
#define NSL 320                 // 4*80 slices
#define TRI2_TOT 36864          // quad-uniform staggered triangle, floats (144 KB)
#define DISP_OFF 0
#define CONF_OFF 81920
#define OCC_OFF  163840
#define CV_OFF   245760
#define CVD_OFF  21217280
#define NU_C (1.0f/512.0f)
#define MU_C (1.0f/512.0f)

// Quad m (rows 4m..4m+3) all have padded length ell(m) = 4 + 32*((m+7)>>3).
// Row start S(i) = Q(m) + (i&3)*ell(m), Q(m) = 16m + 128*G(m),
// G(m) = 4q(q-1) + r*q with q=(m+7)>>3, r=(m+7)&7.
// Properties: S(i) ≡ 4i (mod 32) -> b128 row reads conflict-free; S(i) ≡ 0 (mod 4).
__device__ __forceinline__ int ell_of(int m) { return 4 + (((m + 7) >> 3) << 5); }
__device__ __forceinline__ int S_of(int i) {
  int m = i >> 2;
  int q = (m + 7) >> 3, r = (m + 7) & 7;
  int Q = 16*m + ((q*(q-1)) << 9) + ((r*q) << 7);
  return Q + (i & 3) * ell_of(m);
}

// ---------------- cost-volume GEMM with fused LayerNorm ----------------
__global__ __launch_bounds__(256, 2)
void cv_kernel(const float* __restrict__ feat, const float* __restrict__ lnw,
               const float* __restrict__ lnb, float* __restrict__ cv_out) {
  extern __shared__ float sm[];
  float* As = sm;              // [64][128] k-major
  float* Bs = sm + 64*128;
  __shared__ __align__(16) float rmean[256];
  __shared__ __align__(16) float rrstd[256];
  __shared__ float lwS[128], lbS[128];
  const int t = threadIdx.x;
  const int z = blockIdx.z, b = z / HH, h = z % HH;
  const int i0 = blockIdx.y * 128, j0 = blockIdx.x * 128;
  if (t < 128) { lwS[t] = lnw[t]; lbS[t] = lnb[t]; }
  {
    const int isA = (t < 128);
    const int row = isA ? (i0 + t) : (j0 + (t - 128));
    const int bb  = isA ? b : (b + 4);
    const float* p = feat + ((size_t)bb*CC*HH + (size_t)h)*WW + row;
    float s = 0.f, s2 = 0.f;
    for (int c = 0; c < CC; ++c) {
      float v = p[(size_t)c*HH*WW];
      s += v; s2 = fmaf(v, v, s2);
    }
    float mu  = s * (1.f/CC);
    float var = fmaf(-mu, mu, s2 * (1.f/CC));
    rmean[t] = mu; rrstd[t] = rsqrtf(var + 1e-5f);
  }
  float acc[64];
  #pragma unroll
  for (int q = 0; q < 64; ++q) acc[q] = 0.f;
  const int ty = t >> 4, tx = t & 15;
  const size_t baseA = ((size_t)b*CC*HH + (size_t)h)*WW + i0;
  const size_t baseB = ((size_t)(b+4)*CC*HH + (size_t)h)*WW + j0;
  for (int kc = 0; kc < 2; ++kc) {
    __syncthreads();
    #pragma unroll
    for (int r = 0; r < 8; ++r) {
      int f = r*256 + t;
      int kl = f >> 5, col = (f & 31)*4;
      int ch = kc*64 + kl;
      float lw = lwS[ch], lb = lbS[ch];
      float4 va = *(const float4*)&feat[baseA + (size_t)ch*HH*WW + col];
      float4 rm = *(const float4*)&rmean[col];
      float4 rr = *(const float4*)&rrstd[col];
      va.x = (va.x-rm.x)*rr.x*lw+lb; va.y = (va.y-rm.y)*rr.y*lw+lb;
      va.z = (va.z-rm.z)*rr.z*lw+lb; va.w = (va.w-rm.w)*rr.w*lw+lb;
      *(float4*)&As[kl*128 + col] = va;
      float4 vb = *(const float4*)&feat[baseB + (size_t)ch*HH*WW + col];
      float4 rm2 = *(const float4*)&rmean[128+col];
      float4 rr2 = *(const float4*)&rrstd[128+col];
      vb.x = (vb.x-rm2.x)*rr2.x*lw+lb; vb.y = (vb.y-rm2.y)*rr2.y*lw+lb;
      vb.z = (vb.z-rm2.z)*rr2.z*lw+lb; vb.w = (vb.w-rm2.w)*rr2.w*lw+lb;
      *(float4*)&Bs[kl*128 + col] = vb;
    }
    __syncthreads();
    #pragma unroll 2
    for (int kl = 0; kl < 64; ++kl) {
      float4 a0 = *(const float4*)&As[kl*128 + ty*8];
      float4 a1 = *(const float4*)&As[kl*128 + ty*8 + 4];
      float4 b0 = *(const float4*)&Bs[kl*128 + tx*4];
      float4 b1 = *(const float4*)&Bs[kl*128 + 64 + tx*4];
      float av[8] = {a0.x,a0.y,a0.z,a0.w,a1.x,a1.y,a1.z,a1.w};
      float bv[8] = {b0.x,b0.y,b0.z,b0.w,b1.x,b1.y,b1.z,b1.w};
      #pragma unroll
      for (int rr = 0; rr < 8; ++rr)
        #pragma unroll
        for (int qq = 0; qq < 8; ++qq)
          acc[rr*8+qq] = fmaf(av[rr], bv[qq], acc[rr*8+qq]);
    }
  }
  #pragma unroll
  for (int rr = 0; rr < 8; ++rr) {
    int row = i0 + ty*8 + rr;
    size_t obase = ((size_t)z*256 + row)*256;
    *(float4*)&cv_out[obase + j0 + tx*4] =
        make_float4(acc[rr*8+0],acc[rr*8+1],acc[rr*8+2],acc[rr*8+3]);
    *(float4*)&cv_out[obase + j0 + 64 + tx*4] =
        make_float4(acc[rr*8+4],acc[rr*8+5],acc[rr*8+6],acc[rr*8+7]);
  }
}

// ---------------- downsampled cost volume (h,i strided by 2) ----------------
__global__ __launch_bounds__(256, 2)
void cvd_kernel(const float* __restrict__ feat, const float* __restrict__ lnw,
                const float* __restrict__ lnb, float* __restrict__ cvd_out) {
  extern __shared__ float sm[];
  float* As = sm; float* Bs = sm + 64*128;
  __shared__ __align__(16) float rmean[256];
  __shared__ __align__(16) float rrstd[256];
  __shared__ float lwS[128], lbS[128];
  const int t = threadIdx.x;
  const int z = blockIdx.x, b = z / 40, hd = z % 40, h = 2*hd;
  if (t < 128) { lwS[t] = lnw[t]; lbS[t] = lnb[t]; }
  {
    const int isA = (t < 128);
    const int rowd = isA ? t : (t - 128);
    const int bb = isA ? b : (b + 4);
    const float* p = feat + ((size_t)bb*CC*HH + (size_t)h)*WW + 2*rowd;
    float s = 0.f, s2 = 0.f;
    for (int c = 0; c < CC; ++c) { float v = p[(size_t)c*HH*WW]; s += v; s2 = fmaf(v,v,s2); }
    float mu  = s * (1.f/CC);
    float var = fmaf(-mu, mu, s2 * (1.f/CC));
    rmean[t] = mu; rrstd[t] = rsqrtf(var + 1e-5f);
  }
  float acc[64];
  #pragma unroll
  for (int q = 0; q < 64; ++q) acc[q] = 0.f;
  const int ty = t >> 4, tx = t & 15;
  const size_t baseA = ((size_t)b*CC*HH + (size_t)h)*WW;
  const size_t baseB = ((size_t)(b+4)*CC*HH + (size_t)h)*WW;
  for (int kc = 0; kc < 2; ++kc) {
    __syncthreads();
    #pragma unroll
    for (int r = 0; r < 8; ++r) {
      int f = r*256 + t;
      int kl = f >> 5, col = (f & 31)*4;
      int ch = kc*64 + kl;
      float lw = lwS[ch], lb = lbS[ch];
      const float* pa = &feat[baseA + (size_t)ch*HH*WW + 2*col];
      float4 q0 = *(const float4*)pa;
      float4 q1 = *(const float4*)(pa + 4);
      float4 rm = *(const float4*)&rmean[col];
      float4 rr = *(const float4*)&rrstd[col];
      float4 va = make_float4((q0.x-rm.x)*rr.x*lw+lb, (q0.z-rm.y)*rr.y*lw+lb,
                              (q1.x-rm.z)*rr.z*lw+lb, (q1.z-rm.w)*rr.w*lw+lb);
      *(float4*)&As[kl*128 + col] = va;
      const float* pb = &feat[baseB + (size_t)ch*HH*WW + 2*col];
      float4 s0 = *(const float4*)pb;
      float4 s1 = *(const float4*)(pb + 4);
      float4 rm2 = *(const float4*)&rmean[128+col];
      float4 rr2 = *(const float4*)&rrstd[128+col];
      float4 vb = make_float4((s0.x-rm2.x)*rr2.x*lw+lb, (s0.z-rm2.y)*rr2.y*lw+lb,
                              (s1.x-rm2.z)*rr2.z*lw+lb, (s1.z-rm2.w)*rr2.w*lw+lb);
      *(float4*)&Bs[kl*128 + col] = vb;
    }
    __syncthreads();
    #pragma unroll 2
    for (int kl = 0; kl < 64; ++kl) {
      float4 a0 = *(const float4*)&As[kl*128 + ty*8];
      float4 a1 = *(const float4*)&As[kl*128 + ty*8 + 4];
      float4 b0 = *(const float4*)&Bs[kl*128 + tx*4];
      float4 b1 = *(const float4*)&Bs[kl*128 + 64 + tx*4];
      float av[8] = {a0.x,a0.y,a0.z,a0.w,a1.x,a1.y,a1.z,a1.w};
      float bv[8] = {b0.x,b0.y,b0.z,b0.w,b1.x,b1.y,b1.z,b1.w};
      #pragma unroll
      for (int rr = 0; rr < 8; ++rr)
        #pragma unroll
        for (int qq = 0; qq < 8; ++qq)
          acc[rr*8+qq] = fmaf(av[rr], bv[qq], acc[rr*8+qq]);
    }
  }
  #pragma unroll
  for (int rr = 0; rr < 8; ++rr) {
    int row = ty*8 + rr;
    size_t obase = ((size_t)z*128 + row)*128;
    *(float4*)&cvd_out[obase + tx*4] =
        make_float4(acc[rr*8+0],acc[rr*8+1],acc[rr*8+2],acc[rr*8+3]);
    *(float4*)&cvd_out[obase + 64 + tx*4] =
        make_float4(acc[rr*8+4],acc[rr*8+5],acc[rr*8+6],acc[rr*8+7]);
  }
}

// ---------------- Sinkhorn: balanced 9-quad register stripes -----------------
// Row pairing: thread (j = t&255, c = t>>8) owns row j's quads bk<32 with
// bk≡c (mod 4)  ("direct", count nd)  PLUS row (255-j)'s quads bk>=32 with
// bk≡c (mod 4) above 32 ("overflow", count no).  nd+no <= 9 for all (j,c),
// so the whole triangle lives in eR[9] (36 VGPRs/thread) across 1024 threads.
// Consequences: (1) single global pass (load -> masked max -> exp -> LDS
// write for colsum, values retained in registers for rowsum/epilogue);
// (2) no 64-VGPR eR[16] stripe -> no spill/remat at any plausible budget;
// (3) rowsum/occ/argmax partials routed via buf[8][256]: direct -> rows 0-3
// at index j, overflow -> rows 4-7 at index 255-j.
__global__ __launch_bounds__(1024)
__attribute__((amdgpu_waves_per_eu(4, 4)))
void sink_kernel(const float* __restrict__ cvg, float* __restrict__ out) {
  extern __shared__ float pE[];                 // TRI2_TOT floats
  __shared__ __align__(16) float eu[260];
  __shared__ __align__(16) float ev[260];
  __shared__ __align__(16) float buf[8][256];
  __shared__ float vbS[256];
  __shared__ float redbufU[4], redbufV[4], redbufM[16];
  __shared__ float Msh;
  const int t = threadIdx.x;
  const int z = blockIdx.x;
  const float* cvS = cvg + (size_t)z * 65536;

  const int j   = t & 255;
  const int c   = t >> 8;
  const int jo  = 255 - j;
  const int nbj = (j >> 2) + 1;
  const int bkd = nbj < 32 ? nbj : 32;
  const int nd  = (bkd > c) ? ((bkd - c + 3) >> 2) : 0;       // direct quads
  const int ov  = ((jo >> 2) + 1) - 32;                       // overflow quads in row jo
  const int no  = (ov > c) ? ((ov - c + 3) >> 2) : 0;         // this thread's share
  const int nv  = nd + no;                                    // valid slots (<= 9)
  const int rsR = S_of(j);
  const int rsO = S_of(jo);
  const int coovf = 128 + 4*c - 16*nd;   // overflow col offset = coovf + 16*r

  if (t >= 512 && t < 768) eu[t - 512] = 1.f;
  if (t == 768) eu[256] = 1.f;

  // ---- single pass: global -> registers, masked slice max ----
  float4 eR[9];
  {
    float mx = 0.f;
    #pragma unroll
    for (int r = 0; r < 9; ++r) {
      const bool isd  = r < nd;
      const bool valq = r < nv;
      const int co  = isd ? (4*c + 16*r) : ((coovf + 16*r) & 255);
      const int row = isd ? j : jo;
      float4 v = make_float4(0.f, 0.f, 0.f, 0.f);
      if (valq) {
        v = *(const float4*)&cvS[row*256 + co];
        if (co     <= row) mx = fmaxf(mx, v.x);
        if (co + 1 <= row) mx = fmaxf(mx, v.y);
        if (co + 2 <= row) mx = fmaxf(mx, v.z);
        if (co + 3 <= row) mx = fmaxf(mx, v.w);
      }
      eR[r] = v;                              // raw cv for now
    }
    #pragma unroll
    for (int mm = 32; mm; mm >>= 1) mx = fmaxf(mx, __shfl_xor(mx, mm, 64));
    if ((t & 63) == 0) redbufM[t >> 6] = mx;
  }
  __syncthreads();
  if (t == 0) {
    float m2 = redbufM[0];
    #pragma unroll
    for (int q = 1; q < 16; ++q) m2 = fmaxf(m2, redbufM[q]);
    Msh = m2;
  }
  __syncthreads();
  const float M = Msh;
  const float enM = __expf(-M);

  // ---- exp in registers; write packed triangle to LDS for colsum ----
  #pragma unroll
  for (int r = 0; r < 9; ++r) {
    const bool isd  = r < nd;
    const bool valq = r < nv;
    const int co  = isd ? (4*c + 16*r) : ((coovf + 16*r) & 255);
    const int row = isd ? j : jo;
    const int rs  = isd ? rsR : rsO;
    float4 v = eR[r];
    float4 e;
    e.x = (valq && co     <= row) ? __expf(v.x - M) : 0.f;
    e.y = (valq && co + 1 <= row) ? __expf(v.y - M) : 0.f;
    e.z = (valq && co + 2 <= row) ? __expf(v.z - M) : 0.f;
    e.w = (valq && co + 3 <= row) ? __expf(v.w - M) : 0.f;
    eR[r] = e;
    if (valq) *(float4*)&pE[rs + co] = e;
  }
  __syncthreads();

  for (int it = 0; it < 8; ++it) {
    // ---- phase A: colsum partials (waves 0-7) + S_eu reduce (waves 8-11) ---
    if (t < 512) {
      const int g = t >> 6, lane = t & 63, c0 = 4*(t & 63);
      float4 a = make_float4(0.f, 0.f, 0.f, 0.f);
      #pragma unroll 2
      for (int mq = 0; mq < 32; mq += 2) {
        int i0 = 8*mq + g, i1 = i0 + 8;
        float u0 = eu[i0], u1 = eu[i1];
        int rs0 = S_of(i0), rs1 = S_of(i1);
        if (lane <= (i0 >> 2)) {
          float4 e = *(const float4*)&pE[rs0 + c0];
          a.x = fmaf(e.x, u0, a.x); a.y = fmaf(e.y, u0, a.y);
          a.z = fmaf(e.z, u0, a.z); a.w = fmaf(e.w, u0, a.w);
        }
        if (lane <= (i1 >> 2)) {
          float4 e = *(const float4*)&pE[rs1 + c0];
          a.x = fmaf(e.x, u1, a.x); a.y = fmaf(e.y, u1, a.y);
          a.z = fmaf(e.z, u1, a.z); a.w = fmaf(e.w, u1, a.w);
        }
      }
      *(float4*)&buf[g][c0] = a;
    } else if (t < 768) {
      int tt = t - 512;
      float s = eu[tt];
      #pragma unroll
      for (int mm = 32; mm; mm >>= 1) s += __shfl_xor(s, mm, 64);
      if ((tt & 63) == 0) redbufU[tt >> 6] = s;
    }
    __syncthreads();
    // ---- phase B: ev from column sums; reduce S_ev; pad ev[256] ----
    if (t < 256) {
      float cj = ((buf[0][t] + buf[1][t]) + (buf[2][t] + buf[3][t]))
               + ((buf[4][t] + buf[5][t]) + (buf[6][t] + buf[7][t]))
               + enM * eu[256];
      float evt = NU_C / cj;
      ev[t] = evt;
      float s = evt;
      #pragma unroll
      for (int mm = 32; mm; mm >>= 1) s += __shfl_xor(s, mm, 64);
      if ((t & 63) == 0) redbufV[t >> 6] = s;
    } else if (t == 960) {
      float S = ((redbufU[0] + redbufU[1]) + (redbufU[2] + redbufU[3])) + eu[256];
      ev[256] = 0.5f / (enM * S);
    }
    __syncthreads();
    // ---- phase C: rowsum partials from registers (all 16 waves) ----
    {
      float d0=0.f,d1=0.f,d2=0.f,d3=0.f;
      float o0=0.f,o1=0.f,o2=0.f,o3=0.f;
      #pragma unroll
      for (int r = 0; r < 9; ++r) {
        const int co = (r < nd) ? (4*c + 16*r) : ((coovf + 16*r) & 255);
        float4 ev4 = *(const float4*)&ev[co];
        float4 e = eR[r];
        float p0 = e.x*ev4.x, p1 = e.y*ev4.y, p2 = e.z*ev4.z, p3 = e.w*ev4.w;
        if (r < nd) { d0 += p0; d1 += p1; d2 += p2; d3 += p3; }
        else        { o0 += p0; o1 += p1; o2 += p2; o3 += p3; }
      }
      buf[c][j]      = (d0 + d1) + (d2 + d3);
      buf[4 + c][jo] = (o0 + o1) + (o2 + o3);
    }
    __syncthreads();
    // ---- phase D: eu from row sums; pad eu[256] ----
    if (t < 256) {
      float ri = (((buf[0][t] + buf[1][t]) + (buf[2][t] + buf[3][t]))
                + ((buf[4][t] + buf[5][t]) + (buf[6][t] + buf[7][t])))
               + enM * ev[256];
      eu[t] = MU_C / ri;
    } else if (t == 960) {
      float S = ((redbufV[0] + redbufV[1]) + (redbufV[2] + redbufV[3])) + ev[256];
      eu[256] = 0.5f / (enM * S);
    }
    __syncthreads();
  }

  // ---- epilogue: occ / first-max argmax / conf / corr (from registers) ----
  {
    float d0=0.f,d1=0.f,d2=0.f,d3=0.f;
    float o0=0.f,o1=0.f,o2=0.f,o3=0.f;
    float vmd = -1.f, vmo = -1.f;
    int jmd = 1 << 30, jmo = 1 << 30;
    #pragma unroll
    for (int r = 0; r < 9; ++r) {
      const bool isd = r < nd;
      const int co = isd ? (4*c + 16*r) : ((coovf + 16*r) & 255);
      float4 ev4 = *(const float4*)&ev[co];
      float4 e = eR[r];
      float p0 = e.x*ev4.x, p1 = e.y*ev4.y, p2 = e.z*ev4.z, p3 = e.w*ev4.w;
      if (isd) {
        d0 += p0; d1 += p1; d2 += p2; d3 += p3;
        if (p0 > vmd) { vmd = p0; jmd = co;     }
        if (p1 > vmd) { vmd = p1; jmd = co + 1; }
        if (p2 > vmd) { vmd = p2; jmd = co + 2; }
        if (p3 > vmd) { vmd = p3; jmd = co + 3; }
      } else {
        o0 += p0; o1 += p1; o2 += p2; o3 += p3;
        if (p0 > vmo) { vmo = p0; jmo = co;     }
        if (p1 > vmo) { vmo = p1; jmo = co + 1; }
        if (p2 > vmo) { vmo = p2; jmo = co + 2; }
        if (p3 > vmo) { vmo = p3; jmo = co + 3; }
      }
    }
    buf[c][j]      = (d0 + d1) + (d2 + d3);    // phase A': occ partials
    buf[4 + c][jo] = (o0 + o1) + (o2 + o3);
    __syncthreads();
    if (t < 256) {
      float occT = (((buf[0][t] + buf[1][t]) + (buf[2][t] + buf[3][t]))
                  + ((buf[4][t] + buf[5][t]) + (buf[6][t] + buf[7][t])));
      out[OCC_OFF + z*256 + t] = occT * eu[t] * 512.f;
    }
    __syncthreads();
    buf[c][j]      = vmd;                      // phase B': vmax partials
    buf[4 + c][jo] = vmo;
    __syncthreads();
    if (t < 256)
      vbS[t] = fmaxf(fmaxf(fmaxf(buf[0][t], buf[1][t]), fmaxf(buf[2][t], buf[3][t])),
                     fmaxf(fmaxf(buf[4][t], buf[5][t]), fmaxf(buf[6][t], buf[7][t])));
    __syncthreads();
    ((int*)buf)[c*256 + j]        = (vmd == vbS[j])  ? jmd : (1 << 30);  // phase C'
    ((int*)buf)[(4 + c)*256 + jo] = (vmo == vbS[jo]) ? jmo : (1 << 30);
    __syncthreads();
    if (t < 256) {
      const int* bi = (const int*)buf;
      int jb = min(min(min(bi[t], bi[256 + t]), min(bi[512 + t], bi[768 + t])),
                   min(min(bi[1024 + t], bi[1280 + t]), min(bi[1536 + t], bi[1792 + t])));
      const int rsT = S_of(t);
      const float sc = eu[t] * 512.f;
      float conf = 0.f, corr = 0.f;
      #pragma unroll
      for (int d = 0; d < 5; ++d) {
        int jp = jb + d - 2;
        float wgt = 0.f;
        if (jp >= 0 && jp <= t) wgt = pE[rsT + jp] * ev[jp] * sc;
        conf += wgt;
        corr = fmaf(wgt, (float)jp, corr);
      }
      corr = (corr + 1e-4f) / (conf + 1e-4f);
      out[DISP_OFF + z*256 + t] = (float)t - corr;
      out[CONF_OFF + z*256 + t] = conf;
    }
  }
}

extern "C" void kernel_launch(void* const* d_in, const int* in_sizes, int n_in,
                              void* d_out, int out_size, void* d_ws, size_t ws_size,
                              hipStream_t stream) {
  (void)in_sizes; (void)n_in; (void)out_size; (void)d_ws; (void)ws_size;
  const float* feat = (const float*)d_in[0];
  const float* lnw  = (const float*)d_in[1];
  const float* lnb  = (const float*)d_in[2];
  float* out = (float*)d_out;

  (void)hipFuncSetAttribute((const void*)cv_kernel,
                            hipFuncAttributeMaxDynamicSharedMemorySize, 65536);
  (void)hipFuncSetAttribute((const void*)cvd_kernel,
                            hipFuncAttributeMaxDynamicSharedMemorySize, 65536);
  (void)hipFuncSetAttribute((const void*)sink_kernel,
                            hipFuncAttributeMaxDynamicSharedMemorySize, TRI2_TOT*4);

  cv_kernel<<<dim3(2, 2, NSL), 256, 65536, stream>>>(feat, lnw, lnb, out + CV_OFF);
  sink_kernel<<<dim3(NSL), 1024, TRI2_TOT*4, stream>>>(out + CV_OFF, out);
  cvd_kernel<<<dim3(160), 256, 65536, stream>>>(feat, lnw, lnb, out + CVD_OFF);
}

// Round 2
// 345.492 us; speedup vs baseline: 1.1816x; 1.0175x over previous
//
#include <hip/hip_runtime.h>

#define CC 128
#define HH 80
#define WW 256
#define NSL 320                 // 4*80 slices
#define TRI2_TOT 36864          // quad-uniform staggered triangle, floats (144 KB)
#define DISP_OFF 0
#define CONF_OFF 81920
#define OCC_OFF  163840
#define CV_OFF   245760
#define CVD_OFF  21217280
#define NU_C (1.0f/512.0f)
#define MU_C (1.0f/512.0f)

// Quad m (rows 4m..4m+3) all have padded length ell(m) = 4 + 32*((m+7)>>3).
// Row start S(i) = Q(m) + (i&3)*ell(m), Q(m) = 16m + 128*G(m),
// G(m) = 4q(q-1) + r*q with q=(m+7)>>3, r=(m+7)&7.
// Properties: S(i) ≡ 4i (mod 32) -> b128 row reads conflict-free; S(i) ≡ 0 (mod 4).
__device__ __forceinline__ int ell_of(int m) { return 4 + (((m + 7) >> 3) << 5); }
__device__ __forceinline__ int S_of(int i) {
  int m = i >> 2;
  int q = (m + 7) >> 3, r = (m + 7) & 7;
  int Q = 16*m + ((q*(q-1)) << 9) + ((r*q) << 7);
  return Q + (i & 3) * ell_of(m);
}

// ------------- fused cost-volume GEMM (cv + cvd) with fused LayerNorm --------
// BK=32 chunking: As[32][128]+Bs[32][128] = 32 KB dynamic (+3 KB static) ->
// 4 blocks/CU = 16 waves/CU (was 64 KB -> 2 blocks/CU, Occupancy 19%,
// VALUBusy 42%). K-order ch=0..127 stays sequential -> bitwise-identical.
// z in [0,NSL): cv tile (i0=by*128, j0=bx*128).  z in [NSL,NSL+40): cvd
// block id = (z-NSL)*4 + by*2 + bx -- 160 independent blocks that pack into
// cv's 25%-full second residency round (1280 = 1024 + 256 blocks at 4/CU).
__global__ __launch_bounds__(256, 4)
void cv_fused_kernel(const float* __restrict__ feat, const float* __restrict__ lnw,
                     const float* __restrict__ lnb, float* __restrict__ cv_out,
                     float* __restrict__ cvd_out) {
  extern __shared__ float sm[];
  float* As = sm;              // [32][128] k-major
  float* Bs = sm + 32*128;
  __shared__ __align__(16) float rmean[256];
  __shared__ __align__(16) float rrstd[256];
  __shared__ float lwS[128], lbS[128];
  const int t = threadIdx.x;
  const int zz = blockIdx.z;
  if (t < 128) { lwS[t] = lnw[t]; lbS[t] = lnb[t]; }
  const int ty = t >> 4, tx = t & 15;

  if (zz < NSL) {
    // ---------------- cv ----------------
    const int b = zz / HH, h = zz % HH;
    const int i0 = blockIdx.y * 128, j0 = blockIdx.x * 128;
    {
      const int isA = (t < 128);
      const int row = isA ? (i0 + t) : (j0 + (t - 128));
      const int bb  = isA ? b : (b + 4);
      const float* p = feat + ((size_t)bb*CC*HH + (size_t)h)*WW + row;
      float s = 0.f, s2 = 0.f;
      #pragma unroll 4
      for (int c = 0; c < CC; ++c) {
        float v = p[(size_t)c*HH*WW];
        s += v; s2 = fmaf(v, v, s2);
      }
      float mu  = s * (1.f/CC);
      float var = fmaf(-mu, mu, s2 * (1.f/CC));
      rmean[t] = mu; rrstd[t] = rsqrtf(var + 1e-5f);
    }
    float acc[64];
    #pragma unroll
    for (int q = 0; q < 64; ++q) acc[q] = 0.f;
    const size_t baseA = ((size_t)b*CC*HH + (size_t)h)*WW + i0;
    const size_t baseB = ((size_t)(b+4)*CC*HH + (size_t)h)*WW + j0;
    for (int kc = 0; kc < 4; ++kc) {
      __syncthreads();
      #pragma unroll
      for (int r = 0; r < 4; ++r) {
        int f = r*256 + t;
        int kl = f >> 5, col = (f & 31)*4;
        int ch = kc*32 + kl;
        float lw = lwS[ch], lb = lbS[ch];
        float4 va = *(const float4*)&feat[baseA + (size_t)ch*HH*WW + col];
        float4 rm = *(const float4*)&rmean[col];
        float4 rr = *(const float4*)&rrstd[col];
        va.x = (va.x-rm.x)*rr.x*lw+lb; va.y = (va.y-rm.y)*rr.y*lw+lb;
        va.z = (va.z-rm.z)*rr.z*lw+lb; va.w = (va.w-rm.w)*rr.w*lw+lb;
        *(float4*)&As[kl*128 + col] = va;
        float4 vb = *(const float4*)&feat[baseB + (size_t)ch*HH*WW + col];
        float4 rm2 = *(const float4*)&rmean[128+col];
        float4 rr2 = *(const float4*)&rrstd[128+col];
        vb.x = (vb.x-rm2.x)*rr2.x*lw+lb; vb.y = (vb.y-rm2.y)*rr2.y*lw+lb;
        vb.z = (vb.z-rm2.z)*rr2.z*lw+lb; vb.w = (vb.w-rm2.w)*rr2.w*lw+lb;
        *(float4*)&Bs[kl*128 + col] = vb;
      }
      __syncthreads();
      #pragma unroll 2
      for (int kl = 0; kl < 32; ++kl) {
        float4 a0 = *(const float4*)&As[kl*128 + ty*8];
        float4 a1 = *(const float4*)&As[kl*128 + ty*8 + 4];
        float4 b0 = *(const float4*)&Bs[kl*128 + tx*4];
        float4 b1 = *(const float4*)&Bs[kl*128 + 64 + tx*4];
        float av[8] = {a0.x,a0.y,a0.z,a0.w,a1.x,a1.y,a1.z,a1.w};
        float bv[8] = {b0.x,b0.y,b0.z,b0.w,b1.x,b1.y,b1.z,b1.w};
        #pragma unroll
        for (int rr = 0; rr < 8; ++rr)
          #pragma unroll
          for (int qq = 0; qq < 8; ++qq)
            acc[rr*8+qq] = fmaf(av[rr], bv[qq], acc[rr*8+qq]);
      }
    }
    #pragma unroll
    for (int rr = 0; rr < 8; ++rr) {
      int row = i0 + ty*8 + rr;
      size_t obase = ((size_t)zz*256 + row)*256;
      *(float4*)&cv_out[obase + j0 + tx*4] =
          make_float4(acc[rr*8+0],acc[rr*8+1],acc[rr*8+2],acc[rr*8+3]);
      *(float4*)&cv_out[obase + j0 + 64 + tx*4] =
          make_float4(acc[rr*8+4],acc[rr*8+5],acc[rr*8+6],acc[rr*8+7]);
    }
  } else {
    // ---------------- cvd (h,i strided by 2) ----------------
    const int id = (zz - NSL)*4 + blockIdx.y*2 + blockIdx.x;   // 0..159
    const int b = id / 40, hd = id % 40, h = 2*hd;
    {
      const int isA = (t < 128);
      const int rowd = isA ? t : (t - 128);
      const int bb = isA ? b : (b + 4);
      const float* p = feat + ((size_t)bb*CC*HH + (size_t)h)*WW + 2*rowd;
      float s = 0.f, s2 = 0.f;
      #pragma unroll 4
      for (int c = 0; c < CC; ++c) { float v = p[(size_t)c*HH*WW]; s += v; s2 = fmaf(v,v,s2); }
      float mu  = s * (1.f/CC);
      float var = fmaf(-mu, mu, s2 * (1.f/CC));
      rmean[t] = mu; rrstd[t] = rsqrtf(var + 1e-5f);
    }
    float acc[64];
    #pragma unroll
    for (int q = 0; q < 64; ++q) acc[q] = 0.f;
    const size_t baseA = ((size_t)b*CC*HH + (size_t)h)*WW;
    const size_t baseB = ((size_t)(b+4)*CC*HH + (size_t)h)*WW;
    for (int kc = 0; kc < 4; ++kc) {
      __syncthreads();
      #pragma unroll
      for (int r = 0; r < 4; ++r) {
        int f = r*256 + t;
        int kl = f >> 5, col = (f & 31)*4;
        int ch = kc*32 + kl;
        float lw = lwS[ch], lb = lbS[ch];
        const float* pa = &feat[baseA + (size_t)ch*HH*WW + 2*col];
        float4 q0 = *(const float4*)pa;
        float4 q1 = *(const float4*)(pa + 4);
        float4 rm = *(const float4*)&rmean[col];
        float4 rr = *(const float4*)&rrstd[col];
        float4 va = make_float4((q0.x-rm.x)*rr.x*lw+lb, (q0.z-rm.y)*rr.y*lw+lb,
                                (q1.x-rm.z)*rr.z*lw+lb, (q1.z-rm.w)*rr.w*lw+lb);
        *(float4*)&As[kl*128 + col] = va;
        const float* pb = &feat[baseB + (size_t)ch*HH*WW + 2*col];
        float4 s0 = *(const float4*)pb;
        float4 s1 = *(const float4*)(pb + 4);
        float4 rm2 = *(const float4*)&rmean[128+col];
        float4 rr2 = *(const float4*)&rrstd[128+col];
        float4 vb = make_float4((s0.x-rm2.x)*rr2.x*lw+lb, (s0.z-rm2.y)*rr2.y*lw+lb,
                                (s1.x-rm2.z)*rr2.z*lw+lb, (s1.z-rm2.w)*rr2.w*lw+lb);
        *(float4*)&Bs[kl*128 + col] = vb;
      }
      __syncthreads();
      #pragma unroll 2
      for (int kl = 0; kl < 32; ++kl) {
        float4 a0 = *(const float4*)&As[kl*128 + ty*8];
        float4 a1 = *(const float4*)&As[kl*128 + ty*8 + 4];
        float4 b0 = *(const float4*)&Bs[kl*128 + tx*4];
        float4 b1 = *(const float4*)&Bs[kl*128 + 64 + tx*4];
        float av[8] = {a0.x,a0.y,a0.z,a0.w,a1.x,a1.y,a1.z,a1.w};
        float bv[8] = {b0.x,b0.y,b0.z,b0.w,b1.x,b1.y,b1.z,b1.w};
        #pragma unroll
        for (int rr = 0; rr < 8; ++rr)
          #pragma unroll
          for (int qq = 0; qq < 8; ++qq)
            acc[rr*8+qq] = fmaf(av[rr], bv[qq], acc[rr*8+qq]);
      }
    }
    #pragma unroll
    for (int rr = 0; rr < 8; ++rr) {
      int row = ty*8 + rr;
      size_t obase = ((size_t)id*128 + row)*128;
      *(float4*)&cvd_out[obase + tx*4] =
          make_float4(acc[rr*8+0],acc[rr*8+1],acc[rr*8+2],acc[rr*8+3]);
      *(float4*)&cvd_out[obase + 64 + tx*4] =
          make_float4(acc[rr*8+4],acc[rr*8+5],acc[rr*8+6],acc[rr*8+7]);
    }
  }
}

// ---------------- Sinkhorn: balanced 9-quad register stripes -----------------
// Row pairing: thread (j = t&255, c = t>>8) owns row j's quads bk<32 with
// bk≡c (mod 4)  ("direct", count nd)  PLUS row (255-j)'s quads bk>=32 with
// bk≡c (mod 4) above 32 ("overflow", count no).  nd+no <= 9 for all (j,c),
// so the whole triangle lives in eR[9] (36 VGPRs/thread) across 1024 threads.
__global__ __launch_bounds__(1024)
__attribute__((amdgpu_waves_per_eu(4, 4)))
void sink_kernel(const float* __restrict__ cvg, float* __restrict__ out) {
  extern __shared__ float pE[];                 // TRI2_TOT floats
  __shared__ __align__(16) float eu[260];
  __shared__ __align__(16) float ev[260];
  __shared__ __align__(16) float buf[8][256];
  __shared__ float vbS[256];
  __shared__ float redbufU[4], redbufV[4], redbufM[16];
  __shared__ float Msh;
  const int t = threadIdx.x;
  const int z = blockIdx.x;
  const float* cvS = cvg + (size_t)z * 65536;

  const int j   = t & 255;
  const int c   = t >> 8;
  const int jo  = 255 - j;
  const int nbj = (j >> 2) + 1;
  const int bkd = nbj < 32 ? nbj : 32;
  const int nd  = (bkd > c) ? ((bkd - c + 3) >> 2) : 0;       // direct quads
  const int ov  = ((jo >> 2) + 1) - 32;                       // overflow quads in row jo
  const int no  = (ov > c) ? ((ov - c + 3) >> 2) : 0;         // this thread's share
  const int nv  = nd + no;                                    // valid slots (<= 9)
  const int rsR = S_of(j);
  const int rsO = S_of(jo);
  const int coovf = 128 + 4*c - 16*nd;   // overflow col offset = coovf + 16*r

  if (t >= 512 && t < 768) eu[t - 512] = 1.f;
  if (t == 768) eu[256] = 1.f;

  // ---- single pass: global -> registers, masked slice max ----
  float4 eR[9];
  {
    float mx = 0.f;
    #pragma unroll
    for (int r = 0; r < 9; ++r) {
      const bool isd  = r < nd;
      const bool valq = r < nv;
      const int co  = isd ? (4*c + 16*r) : ((coovf + 16*r) & 255);
      const int row = isd ? j : jo;
      float4 v = make_float4(0.f, 0.f, 0.f, 0.f);
      if (valq) {
        v = *(const float4*)&cvS[row*256 + co];
        if (co     <= row) mx = fmaxf(mx, v.x);
        if (co + 1 <= row) mx = fmaxf(mx, v.y);
        if (co + 2 <= row) mx = fmaxf(mx, v.z);
        if (co + 3 <= row) mx = fmaxf(mx, v.w);
      }
      eR[r] = v;                              // raw cv for now
    }
    #pragma unroll
    for (int mm = 32; mm; mm >>= 1) mx = fmaxf(mx, __shfl_xor(mx, mm, 64));
    if ((t & 63) == 0) redbufM[t >> 6] = mx;
  }
  __syncthreads();
  if (t == 0) {
    float m2 = redbufM[0];
    #pragma unroll
    for (int q = 1; q < 16; ++q) m2 = fmaxf(m2, redbufM[q]);
    Msh = m2;
  }
  __syncthreads();
  const float M = Msh;
  const float enM = __expf(-M);

  // ---- exp in registers; write packed triangle to LDS for colsum ----
  #pragma unroll
  for (int r = 0; r < 9; ++r) {
    const bool isd  = r < nd;
    const bool valq = r < nv;
    const int co  = isd ? (4*c + 16*r) : ((coovf + 16*r) & 255);
    const int row = isd ? j : jo;
    const int rs  = isd ? rsR : rsO;
    float4 v = eR[r];
    float4 e;
    e.x = (valq && co     <= row) ? __expf(v.x - M) : 0.f;
    e.y = (valq && co + 1 <= row) ? __expf(v.y - M) : 0.f;
    e.z = (valq && co + 2 <= row) ? __expf(v.z - M) : 0.f;
    e.w = (valq && co + 3 <= row) ? __expf(v.w - M) : 0.f;
    eR[r] = e;
    if (valq) *(float4*)&pE[rs + co] = e;
  }
  __syncthreads();

  for (int it = 0; it < 8; ++it) {
    // ---- phase A: colsum partials (waves 0-7) + S_eu reduce (waves 8-11) ---
    if (t < 512) {
      const int g = t >> 6, lane = t & 63, c0 = 4*(t & 63);
      float4 a = make_float4(0.f, 0.f, 0.f, 0.f);
      #pragma unroll 2
      for (int mq = 0; mq < 32; mq += 2) {
        int i0 = 8*mq + g, i1 = i0 + 8;
        float u0 = eu[i0], u1 = eu[i1];
        int rs0 = S_of(i0), rs1 = S_of(i1);
        if (lane <= (i0 >> 2)) {
          float4 e = *(const float4*)&pE[rs0 + c0];
          a.x = fmaf(e.x, u0, a.x); a.y = fmaf(e.y, u0, a.y);
          a.z = fmaf(e.z, u0, a.z); a.w = fmaf(e.w, u0, a.w);
        }
        if (lane <= (i1 >> 2)) {
          float4 e = *(const float4*)&pE[rs1 + c0];
          a.x = fmaf(e.x, u1, a.x); a.y = fmaf(e.y, u1, a.y);
          a.z = fmaf(e.z, u1, a.z); a.w = fmaf(e.w, u1, a.w);
        }
      }
      *(float4*)&buf[g][c0] = a;
    } else if (t < 768) {
      int tt = t - 512;
      float s = eu[tt];
      #pragma unroll
      for (int mm = 32; mm; mm >>= 1) s += __shfl_xor(s, mm, 64);
      if ((tt & 63) == 0) redbufU[tt >> 6] = s;
    }
    __syncthreads();
    // ---- phase B: ev from column sums; reduce S_ev; pad ev[256] ----
    if (t < 256) {
      float cj = ((buf[0][t] + buf[1][t]) + (buf[2][t] + buf[3][t]))
               + ((buf[4][t] + buf[5][t]) + (buf[6][t] + buf[7][t]))
               + enM * eu[256];
      float evt = NU_C / cj;
      ev[t] = evt;
      float s = evt;
      #pragma unroll
      for (int mm = 32; mm; mm >>= 1) s += __shfl_xor(s, mm, 64);
      if ((t & 63) == 0) redbufV[t >> 6] = s;
    } else if (t == 960) {
      float S = ((redbufU[0] + redbufU[1]) + (redbufU[2] + redbufU[3])) + eu[256];
      ev[256] = 0.5f / (enM * S);
    }
    __syncthreads();
    // ---- phase C: rowsum partials from registers (all 16 waves) ----
    {
      float d0=0.f,d1=0.f,d2=0.f,d3=0.f;
      float o0=0.f,o1=0.f,o2=0.f,o3=0.f;
      #pragma unroll
      for (int r = 0; r < 9; ++r) {
        const int co = (r < nd) ? (4*c + 16*r) : ((coovf + 16*r) & 255);
        float4 ev4 = *(const float4*)&ev[co];
        float4 e = eR[r];
        float p0 = e.x*ev4.x, p1 = e.y*ev4.y, p2 = e.z*ev4.z, p3 = e.w*ev4.w;
        if (r < nd) { d0 += p0; d1 += p1; d2 += p2; d3 += p3; }
        else        { o0 += p0; o1 += p1; o2 += p2; o3 += p3; }
      }
      buf[c][j]      = (d0 + d1) + (d2 + d3);
      buf[4 + c][jo] = (o0 + o1) + (o2 + o3);
    }
    __syncthreads();
    // ---- phase D: eu from row sums; pad eu[256] ----
    if (t < 256) {
      float ri = (((buf[0][t] + buf[1][t]) + (buf[2][t] + buf[3][t]))
                + ((buf[4][t] + buf[5][t]) + (buf[6][t] + buf[7][t])))
               + enM * ev[256];
      eu[t] = MU_C / ri;
    } else if (t == 960) {
      float S = ((redbufV[0] + redbufV[1]) + (redbufV[2] + redbufV[3])) + ev[256];
      eu[256] = 0.5f / (enM * S);
    }
    __syncthreads();
  }

  // ---- epilogue: occ / first-max argmax / conf / corr (from registers) ----
  {
    float d0=0.f,d1=0.f,d2=0.f,d3=0.f;
    float o0=0.f,o1=0.f,o2=0.f,o3=0.f;
    float vmd = -1.f, vmo = -1.f;
    int jmd = 1 << 30, jmo = 1 << 30;
    #pragma unroll
    for (int r = 0; r < 9; ++r) {
      const bool isd = r < nd;
      const int co = isd ? (4*c + 16*r) : ((coovf + 16*r) & 255);
      float4 ev4 = *(const float4*)&ev[co];
      float4 e = eR[r];
      float p0 = e.x*ev4.x, p1 = e.y*ev4.y, p2 = e.z*ev4.z, p3 = e.w*ev4.w;
      if (isd) {
        d0 += p0; d1 += p1; d2 += p2; d3 += p3;
        if (p0 > vmd) { vmd = p0; jmd = co;     }
        if (p1 > vmd) { vmd = p1; jmd = co + 1; }
        if (p2 > vmd) { vmd = p2; jmd = co + 2; }
        if (p3 > vmd) { vmd = p3; jmd = co + 3; }
      } else {
        o0 += p0; o1 += p1; o2 += p2; o3 += p3;
        if (p0 > vmo) { vmo = p0; jmo = co;     }
        if (p1 > vmo) { vmo = p1; jmo = co + 1; }
        if (p2 > vmo) { vmo = p2; jmo = co + 2; }
        if (p3 > vmo) { vmo = p3; jmo = co + 3; }
      }
    }
    buf[c][j]      = (d0 + d1) + (d2 + d3);    // phase A': occ partials
    buf[4 + c][jo] = (o0 + o1) + (o2 + o3);
    __syncthreads();
    if (t < 256) {
      float occT = (((buf[0][t] + buf[1][t]) + (buf[2][t] + buf[3][t]))
                  + ((buf[4][t] + buf[5][t]) + (buf[6][t] + buf[7][t])));
      out[OCC_OFF + z*256 + t] = occT * eu[t] * 512.f;
    }
    __syncthreads();
    buf[c][j]      = vmd;                      // phase B': vmax partials
    buf[4 + c][jo] = vmo;
    __syncthreads();
    if (t < 256)
      vbS[t] = fmaxf(fmaxf(fmaxf(buf[0][t], buf[1][t]), fmaxf(buf[2][t], buf[3][t])),
                     fmaxf(fmaxf(buf[4][t], buf[5][t]), fmaxf(buf[6][t], buf[7][t])));
    __syncthreads();
    ((int*)buf)[c*256 + j]        = (vmd == vbS[j])  ? jmd : (1 << 30);  // phase C'
    ((int*)buf)[(4 + c)*256 + jo] = (vmo == vbS[jo]) ? jmo : (1 << 30);
    __syncthreads();
    if (t < 256) {
      const int* bi = (const int*)buf;
      int jb = min(min(min(bi[t], bi[256 + t]), min(bi[512 + t], bi[768 + t])),
                   min(min(bi[1024 + t], bi[1280 + t]), min(bi[1536 + t], bi[1792 + t])));
      const int rsT = S_of(t);
      const float sc = eu[t] * 512.f;
      float conf = 0.f, corr = 0.f;
      #pragma unroll
      for (int d = 0; d < 5; ++d) {
        int jp = jb + d - 2;
        float wgt = 0.f;
        if (jp >= 0 && jp <= t) wgt = pE[rsT + jp] * ev[jp] * sc;
        conf += wgt;
        corr = fmaf(wgt, (float)jp, corr);
      }
      corr = (corr + 1e-4f) / (conf + 1e-4f);
      out[DISP_OFF + z*256 + t] = (float)t - corr;
      out[CONF_OFF + z*256 + t] = conf;
    }
  }
}

extern "C" void kernel_launch(void* const* d_in, const int* in_sizes, int n_in,
                              void* d_out, int out_size, void* d_ws, size_t ws_size,
                              hipStream_t stream) {
  (void)in_sizes; (void)n_in; (void)out_size; (void)d_ws; (void)ws_size;
  const float* feat = (const float*)d_in[0];
  const float* lnw  = (const float*)d_in[1];
  const float* lnb  = (const float*)d_in[2];
  float* out = (float*)d_out;

  (void)hipFuncSetAttribute((const void*)cv_fused_kernel,
                            hipFuncAttributeMaxDynamicSharedMemorySize, 32768);
  (void)hipFuncSetAttribute((const void*)sink_kernel,
                            hipFuncAttributeMaxDynamicSharedMemorySize, TRI2_TOT*4);

  cv_fused_kernel<<<dim3(2, 2, NSL + 40), 256, 32768, stream>>>(
      feat, lnw, lnb, out + CV_OFF, out + CVD_OFF);
  sink_kernel<<<dim3(NSL), 1024, TRI2_TOT*4, stream>>>(out + CV_OFF, out);
}